// Round 2
// baseline (502.697 us; speedup 1.0000x reference)
//
#include <hip/hip_runtime.h>
#include <hip/hip_bf16.h>
#include <cstddef>

#define LRELU_SLOPE 0.2f
#define EPS_DEN 1e-16f

__device__ __forceinline__ float lrelu(float v) { return v > 0.f ? v : LRELU_SLOPE * v; }

// ---------------------------------------------------------------------------
// GEMM: C[M,NC] = A[M,K] @ W[K,NC]. 64 rows/block, all NC cols, BK=32.
// 256 threads as 16x16; each thread owns 4 rows x (NC/16) cols.
// ---------------------------------------------------------------------------
template <int K, int NC>
__global__ __launch_bounds__(256) void gemm_k(const float* __restrict__ A,
                                              const float* __restrict__ W,
                                              float* __restrict__ C, int M) {
  constexpr int CPT = NC / 16;  // cols per thread (12 for 192, 4 for 64)
  __shared__ float As[64][36];
  __shared__ float Ws[32][NC];
  const int tx = threadIdx.x & 15;
  const int ty = threadIdx.x >> 4;
  const int row0 = blockIdx.x * 64;

  float acc[4][CPT];
#pragma unroll
  for (int i = 0; i < 4; ++i)
#pragma unroll
    for (int j = 0; j < CPT; ++j) acc[i][j] = 0.f;

  for (int k0 = 0; k0 < K; k0 += 32) {
    {  // A tile 64x32: 2048 floats = 256 threads x 8 floats (2x float4)
      int r = threadIdx.x >> 2, c0 = (threadIdx.x & 3) * 8;
      int gr = row0 + r;
      float4 v0 = make_float4(0.f, 0.f, 0.f, 0.f);
      float4 v1 = make_float4(0.f, 0.f, 0.f, 0.f);
      if (gr < M) {
        v0 = *reinterpret_cast<const float4*>(&A[(size_t)gr * K + k0 + c0]);
        v1 = *reinterpret_cast<const float4*>(&A[(size_t)gr * K + k0 + c0 + 4]);
      }
      *reinterpret_cast<float4*>(&As[r][c0]) = v0;
      *reinterpret_cast<float4*>(&As[r][c0 + 4]) = v1;
    }
    {  // W tile 32xNC
      constexpr int NW4 = NC / 4;
#pragma unroll
      for (int i = 0; i < (32 * NW4) / 256; ++i) {
        int idx = threadIdx.x + i * 256;
        int kk = idx / NW4, c4 = (idx % NW4) * 4;
        *reinterpret_cast<float4*>(&Ws[kk][c4]) =
            *reinterpret_cast<const float4*>(&W[(size_t)(k0 + kk) * NC + c4]);
      }
    }
    __syncthreads();
#pragma unroll
    for (int kk = 0; kk < 32; ++kk) {
      float a[4];
#pragma unroll
      for (int i = 0; i < 4; ++i) a[i] = As[ty * 4 + i][kk];
      float w[CPT];
#pragma unroll
      for (int j = 0; j < CPT; j += 4) {
        float4 wv = *reinterpret_cast<const float4*>(&Ws[kk][tx * CPT + j]);
        w[j] = wv.x; w[j + 1] = wv.y; w[j + 2] = wv.z; w[j + 3] = wv.w;
      }
#pragma unroll
      for (int i = 0; i < 4; ++i)
#pragma unroll
        for (int j = 0; j < CPT; ++j) acc[i][j] = fmaf(a[i], w[j], acc[i][j]);
    }
    __syncthreads();
  }
#pragma unroll
  for (int i = 0; i < 4; ++i) {
    int gr = row0 + ty * 4 + i;
    if (gr < M) {
#pragma unroll
      for (int j = 0; j < CPT; j += 4) {
        float4 v = make_float4(acc[i][j], acc[i][j + 1], acc[i][j + 2], acc[i][j + 3]);
        *reinterpret_cast<float4*>(&C[(size_t)gr * NC + tx * CPT + j]) = v;
      }
    }
  }
}

// ---------------------------------------------------------------------------
// Per-row attention dot products: a_s[row,h] = sum_c H[row,h,c]*asrc[h,c]
// One wave per row; 64 lanes = 64 channels per head.
// ---------------------------------------------------------------------------
template <int HEADS>
__global__ __launch_bounds__(256) void attn_dots_k(const float* __restrict__ H,
                                                   const float* __restrict__ asrc,
                                                   const float* __restrict__ adst,
                                                   float* __restrict__ a_s,
                                                   float* __restrict__ a_d, int Nn) {
  int wave = threadIdx.x >> 6, lane = threadIdx.x & 63;
  int row = blockIdx.x * 4 + wave;
  if (row >= Nn) return;
  const float* hp = H + (size_t)row * HEADS * 64;
  float s[HEADS], d[HEADS];
#pragma unroll
  for (int h = 0; h < HEADS; ++h) {
    float v = hp[h * 64 + lane];
    s[h] = v * asrc[h * 64 + lane];
    d[h] = v * adst[h * 64 + lane];
  }
#pragma unroll
  for (int h = 0; h < HEADS; ++h) {
    for (int o = 32; o; o >>= 1) {
      s[h] += __shfl_xor(s[h], o);
      d[h] += __shfl_xor(d[h], o);
    }
  }
  if (lane == 0) {
#pragma unroll
    for (int h = 0; h < HEADS; ++h) {
      a_s[(size_t)row * HEADS + h] = s[h];
      a_d[(size_t)row * HEADS + h] = d[h];
    }
  }
}

// ---------------------------------------------------------------------------
// CSR build over edges + self-loops (ET = E + N edges total)
// ---------------------------------------------------------------------------
__global__ __launch_bounds__(256) void deg_count_k(const int* __restrict__ ei, int E, int Nn,
                                                   int* __restrict__ deg) {
  int e = blockIdx.x * blockDim.x + threadIdx.x;
  int ET = E + Nn;
  if (e >= ET) return;
  int dst = (e < E) ? ei[E + e] : (e - E);
  atomicAdd(&deg[dst], 1);
}

__global__ __launch_bounds__(1024) void scan_k(const int* __restrict__ deg, int* __restrict__ off,
                                               int* __restrict__ cursor, int Nn) {
  __shared__ int part[1024];
  int t = threadIdx.x;
  int per = (Nn + 1023) >> 10;
  int b = t * per, e = min(b + per, Nn);
  int sum = 0;
  for (int i = b; i < e; ++i) sum += deg[i];
  part[t] = sum;
  __syncthreads();
  for (int o = 1; o < 1024; o <<= 1) {
    int v = (t >= o) ? part[t - o] : 0;
    __syncthreads();
    part[t] += v;
    __syncthreads();
  }
  int run = (t == 0) ? 0 : part[t - 1];
  for (int i = b; i < e; ++i) {
    off[i] = run;
    cursor[i] = run;
    run += deg[i];
  }
  if (t == 1023) off[Nn] = part[1023];
}

__global__ __launch_bounds__(256) void fill_k(const int* __restrict__ ei, int E, int Nn,
                                              int* __restrict__ cursor, int* __restrict__ srcs) {
  int e = blockIdx.x * blockDim.x + threadIdx.x;
  int ET = E + Nn;
  if (e >= ET) return;
  int src, dst;
  if (e < E) { src = ei[e]; dst = ei[E + e]; }
  else { src = e - E; dst = e - E; }
  int pos = atomicAdd(&cursor[dst], 1);
  srcs[pos] = src;
}

// ---------------------------------------------------------------------------
// Layer-1 aggregation: wave per dst node, 3 heads x 64 ch. Softmax without
// max-subtraction (logits are O(8), safe in f32); bias + ELU fused.
// ---------------------------------------------------------------------------
__global__ __launch_bounds__(256) void agg1_k(const float* __restrict__ H,
                                              const float* __restrict__ a_s,
                                              const float* __restrict__ a_d,
                                              const int* __restrict__ off,
                                              const int* __restrict__ srcs,
                                              const float* __restrict__ bias,
                                              float* __restrict__ out, int Nn) {
  int wave = threadIdx.x >> 6, lane = threadIdx.x & 63;
  int node = blockIdx.x * 4 + wave;
  if (node >= Nn) return;
  float ad0 = a_d[(size_t)node * 3 + 0];
  float ad1 = a_d[(size_t)node * 3 + 1];
  float ad2 = a_d[(size_t)node * 3 + 2];
  int b = off[node], e = off[node + 1];
  float acc0 = 0.f, acc1 = 0.f, acc2 = 0.f, ts0 = 0.f, ts1 = 0.f, ts2 = 0.f;
  for (int p = b; p < e; ++p) {
    int s = srcs[p];
    const float* asp = a_s + (size_t)s * 3;
    float t0 = __expf(lrelu(asp[0] + ad0));
    float t1 = __expf(lrelu(asp[1] + ad1));
    float t2 = __expf(lrelu(asp[2] + ad2));
    const float* hp = H + (size_t)s * 192;
    acc0 = fmaf(t0, hp[lane], acc0);
    acc1 = fmaf(t1, hp[64 + lane], acc1);
    acc2 = fmaf(t2, hp[128 + lane], acc2);
    ts0 += t0; ts1 += t1; ts2 += t2;
  }
  float o0 = acc0 / (ts0 + EPS_DEN) + bias[lane];
  float o1 = acc1 / (ts1 + EPS_DEN) + bias[64 + lane];
  float o2 = acc2 / (ts2 + EPS_DEN) + bias[128 + lane];
  o0 = o0 > 0.f ? o0 : expm1f(o0);
  o1 = o1 > 0.f ? o1 : expm1f(o1);
  o2 = o2 > 0.f ? o2 : expm1f(o2);
  out[(size_t)node * 192 + lane] = o0;
  out[(size_t)node * 192 + 64 + lane] = o1;
  out[(size_t)node * 192 + 128 + lane] = o2;
}

// ---------------------------------------------------------------------------
// Layer-2 aggregation: wave per dst node, single head x 64 ch. Writes d_out.
// ---------------------------------------------------------------------------
__global__ __launch_bounds__(256) void agg2_k(const float* __restrict__ H,
                                              const float* __restrict__ a_s,
                                              const float* __restrict__ a_d,
                                              const int* __restrict__ off,
                                              const int* __restrict__ srcs,
                                              const float* __restrict__ bias,
                                              float* __restrict__ out, int Nn) {
  int wave = threadIdx.x >> 6, lane = threadIdx.x & 63;
  int node = blockIdx.x * 4 + wave;
  if (node >= Nn) return;
  float ad = a_d[node];
  int b = off[node], e = off[node + 1];
  float acc = 0.f, ts = 0.f;
  for (int p = b; p < e; ++p) {
    int s = srcs[p];
    float t = __expf(lrelu(a_s[s] + ad));
    acc = fmaf(t, H[(size_t)s * 64 + lane], acc);
    ts += t;
  }
  out[(size_t)node * 64 + lane] = acc / (ts + EPS_DEN) + bias[lane];
}

// ---------------------------------------------------------------------------
extern "C" void kernel_launch(void* const* d_in, const int* in_sizes, int n_in,
                              void* d_out, int out_size, void* d_ws, size_t ws_size,
                              hipStream_t stream) {
  const float* x = (const float*)d_in[0];
  const int* ei = (const int*)d_in[1];
  const float* W1 = (const float*)d_in[2];
  const float* att_src1 = (const float*)d_in[3];
  const float* att_dst1 = (const float*)d_in[4];
  const float* b1 = (const float*)d_in[5];
  const float* W2 = (const float*)d_in[6];
  const float* att_src2 = (const float*)d_in[7];
  const float* att_dst2 = (const float*)d_in[8];
  const float* b2 = (const float*)d_in[9];

  const int IN = 128, HEADS = 3, HID = 64, OUT = 64;
  const int HC1 = HEADS * HID;  // 192
  const int N = in_sizes[0] / IN;
  const int E = in_sizes[1] / 2;
  const int ET = E + N;

  // workspace layout (floats)
  float* ws = (float*)d_ws;
  float* h1_pre = ws;                      // N*192
  float* h1_post = h1_pre + (size_t)N * HC1;  // N*192
  float* h2_pre = h1_post + (size_t)N * HC1;  // N*64
  float* a_s1 = h2_pre + (size_t)N * OUT;     // N*3
  float* a_d1 = a_s1 + (size_t)N * HEADS;
  float* a_s2 = a_d1 + (size_t)N * HEADS;     // N
  float* a_d2 = a_s2 + N;
  int* deg = (int*)(a_d2 + N);             // N
  int* off = deg + N;                      // N+1
  int* cursor = off + (N + 1);             // N
  int* srcs = cursor + N;                  // ET

  float* outp = (float*)d_out;

  int gemm_blocks = (N + 63) / 64;
  int row_blocks = (N + 3) / 4;
  int edge_blocks = (ET + 255) / 256;

  // CSR build (graph identical for both layers)
  hipMemsetAsync(deg, 0, (size_t)N * sizeof(int), stream);
  deg_count_k<<<edge_blocks, 256, 0, stream>>>(ei, E, N, deg);
  scan_k<<<1, 1024, 0, stream>>>(deg, off, cursor, N);
  fill_k<<<edge_blocks, 256, 0, stream>>>(ei, E, N, cursor, srcs);

  // Layer 1
  gemm_k<128, 192><<<gemm_blocks, 256, 0, stream>>>(x, W1, h1_pre, N);
  attn_dots_k<3><<<row_blocks, 256, 0, stream>>>(h1_pre, att_src1, att_dst1, a_s1, a_d1, N);
  agg1_k<<<row_blocks, 256, 0, stream>>>(h1_pre, a_s1, a_d1, off, srcs, b1, h1_post, N);

  // Layer 2
  gemm_k<192, 64><<<gemm_blocks, 256, 0, stream>>>(h1_post, W2, h2_pre, N);
  attn_dots_k<1><<<row_blocks, 256, 0, stream>>>(h2_pre, att_src2, att_dst2, a_s2, a_d2, N);
  agg2_k<<<row_blocks, 256, 0, stream>>>(h2_pre, a_s2, a_d2, off, srcs, b2, outp, N);

  (void)n_in; (void)out_size; (void)ws_size;
}

// Round 3
// 328.248 us; speedup vs baseline: 1.5315x; 1.5315x over previous
//
#include <hip/hip_runtime.h>
#include <hip/hip_bf16.h>
#include <cstddef>

#define LRELU_SLOPE 0.2f
#define EPS_DEN 1e-16f

__device__ __forceinline__ float lrelu(float v) { return v > 0.f ? v : LRELU_SLOPE * v; }
__device__ __forceinline__ float bf2f(unsigned short u) {
  return __uint_as_float((unsigned int)u << 16);
}
__device__ __forceinline__ unsigned short f2bf(float f) {
  // round-to-nearest-even bf16
  unsigned int x = __float_as_uint(f);
  unsigned int r = x + 0x7fff + ((x >> 16) & 1);
  return (unsigned short)(r >> 16);
}

// ---------------------------------------------------------------------------
// GEMM: C[M,NC] = A[M,K] @ W[K,NC], output quantized to bf16.
// Fused epilogue also computes a_s[row,h] = sum_c h*asrc[h,c] (and a_d) in f32.
// 64 rows/block, 256 threads as 16x16; thread owns 4 rows x (NC/16) cols.
// ---------------------------------------------------------------------------
template <int K, int NC>
__global__ __launch_bounds__(256) void gemm_k(const float* __restrict__ A,
                                              const float* __restrict__ W,
                                              unsigned short* __restrict__ Cb,
                                              const float* __restrict__ asrc,
                                              const float* __restrict__ adst,
                                              float* __restrict__ a_s,
                                              float* __restrict__ a_d, int M) {
  constexpr int CPT = NC / 16;     // cols per thread (12 for 192, 4 for 64)
  constexpr int HEADS = NC / 64;   // 3 or 1
  __shared__ float As[64][36];
  __shared__ float Ws[32][NC];
  const int tx = threadIdx.x & 15;
  const int ty = threadIdx.x >> 4;
  const int row0 = blockIdx.x * 64;

  float acc[4][CPT];
#pragma unroll
  for (int i = 0; i < 4; ++i)
#pragma unroll
    for (int j = 0; j < CPT; ++j) acc[i][j] = 0.f;

  for (int k0 = 0; k0 < K; k0 += 32) {
    {  // A tile 64x32: 2048 floats = 256 threads x 8 floats (2x float4)
      int r = threadIdx.x >> 2, c0 = (threadIdx.x & 3) * 8;
      int gr = row0 + r;
      float4 v0 = make_float4(0.f, 0.f, 0.f, 0.f);
      float4 v1 = make_float4(0.f, 0.f, 0.f, 0.f);
      if (gr < M) {
        v0 = *reinterpret_cast<const float4*>(&A[(size_t)gr * K + k0 + c0]);
        v1 = *reinterpret_cast<const float4*>(&A[(size_t)gr * K + k0 + c0 + 4]);
      }
      *reinterpret_cast<float4*>(&As[r][c0]) = v0;
      *reinterpret_cast<float4*>(&As[r][c0 + 4]) = v1;
    }
    {  // W tile 32xNC
      constexpr int NW4 = NC / 4;
#pragma unroll
      for (int i = 0; i < (32 * NW4) / 256; ++i) {
        int idx = threadIdx.x + i * 256;
        int kk = idx / NW4, c4 = (idx % NW4) * 4;
        *reinterpret_cast<float4*>(&Ws[kk][c4]) =
            *reinterpret_cast<const float4*>(&W[(size_t)(k0 + kk) * NC + c4]);
      }
    }
    __syncthreads();
#pragma unroll
    for (int kk = 0; kk < 32; ++kk) {
      float a[4];
#pragma unroll
      for (int i = 0; i < 4; ++i) a[i] = As[ty * 4 + i][kk];
      float w[CPT];
#pragma unroll
      for (int j = 0; j < CPT; j += 4) {
        float4 wv = *reinterpret_cast<const float4*>(&Ws[kk][tx * CPT + j]);
        w[j] = wv.x; w[j + 1] = wv.y; w[j + 2] = wv.z; w[j + 3] = wv.w;
      }
#pragma unroll
      for (int i = 0; i < 4; ++i)
#pragma unroll
        for (int j = 0; j < CPT; ++j) acc[i][j] = fmaf(a[i], w[j], acc[i][j]);
    }
    __syncthreads();
  }

  // ---- epilogue A: attention dot partials in f32, reduced across tx ----
  float ps[4][HEADS], pd[4][HEADS];
#pragma unroll
  for (int i = 0; i < 4; ++i)
#pragma unroll
    for (int h = 0; h < HEADS; ++h) { ps[i][h] = 0.f; pd[i][h] = 0.f; }
#pragma unroll
  for (int j = 0; j < CPT; ++j) {
    int c = tx * CPT + j;
    int h = c >> 6;
    float av = asrc[c], dv = adst[c];
#pragma unroll
    for (int i = 0; i < 4; ++i) {
      ps[i][h] = fmaf(acc[i][j], av, ps[i][h]);
      pd[i][h] = fmaf(acc[i][j], dv, pd[i][h]);
    }
  }
#pragma unroll
  for (int o = 1; o < 16; o <<= 1) {
#pragma unroll
    for (int i = 0; i < 4; ++i)
#pragma unroll
      for (int h = 0; h < HEADS; ++h) {
        ps[i][h] += __shfl_xor(ps[i][h], o);
        pd[i][h] += __shfl_xor(pd[i][h], o);
      }
  }
  if (tx == 0) {
#pragma unroll
    for (int i = 0; i < 4; ++i) {
      int gr = row0 + ty * 4 + i;
      if (gr < M) {
#pragma unroll
        for (int h = 0; h < HEADS; ++h) {
          a_s[(size_t)gr * HEADS + h] = ps[i][h];
          a_d[(size_t)gr * HEADS + h] = pd[i][h];
        }
      }
    }
  }

  // ---- epilogue B: bf16 store ----
#pragma unroll
  for (int i = 0; i < 4; ++i) {
    int gr = row0 + ty * 4 + i;
    if (gr < M) {
#pragma unroll
      for (int j = 0; j < CPT; j += 2) {
        unsigned int u = (unsigned int)f2bf(acc[i][j]) |
                         ((unsigned int)f2bf(acc[i][j + 1]) << 16);
        *reinterpret_cast<unsigned int*>(&Cb[(size_t)gr * NC + tx * CPT + j]) = u;
      }
    }
  }
}

// ---------------------------------------------------------------------------
// CSR build over edges + self-loops (ET = E + N edges total)
// ---------------------------------------------------------------------------
__global__ __launch_bounds__(256) void deg_count_k(const int* __restrict__ ei, int E, int Nn,
                                                   int* __restrict__ deg) {
  int e = blockIdx.x * blockDim.x + threadIdx.x;
  int ET = E + Nn;
  if (e >= ET) return;
  int dst = (e < E) ? ei[E + e] : (e - E);
  atomicAdd(&deg[dst], 1);
}

// hierarchical scan: 1024 nodes/block (256 thr x 4)
__global__ __launch_bounds__(256) void scan1_k(const int* __restrict__ deg,
                                               int* __restrict__ loc,
                                               int* __restrict__ bsum, int Nn) {
  __shared__ int part[256];
  int t = threadIdx.x;
  int base = blockIdx.x * 1024 + t * 4;
  int v[4];
  int s = 0;
#pragma unroll
  for (int k = 0; k < 4; ++k) {
    int idx = base + k;
    v[k] = (idx < Nn) ? deg[idx] : 0;
    s += v[k];
  }
  part[t] = s;
  __syncthreads();
  for (int o = 1; o < 256; o <<= 1) {
    int u = (t >= o) ? part[t - o] : 0;
    __syncthreads();
    part[t] += u;
    __syncthreads();
  }
  int run = (t == 0) ? 0 : part[t - 1];
#pragma unroll
  for (int k = 0; k < 4; ++k) {
    int idx = base + k;
    if (idx < Nn) loc[idx] = run;
    run += v[k];
  }
  if (t == 255) bsum[blockIdx.x] = part[255];
}

__global__ __launch_bounds__(64) void scan2_k(int* __restrict__ bsum, int nblk) {
  int t = threadIdx.x;
  int v = (t < nblk) ? bsum[t] : 0;
  for (int o = 1; o < 64; o <<= 1) {
    int u = __shfl_up(v, o);
    if (t >= o) v += u;
  }
  if (t < nblk) bsum[t] = v;  // inclusive block sums
}

__global__ __launch_bounds__(256) void scan3_k(const int* __restrict__ loc,
                                               const int* __restrict__ bsum,
                                               int* __restrict__ off,
                                               int* __restrict__ cursor, int Nn, int ET) {
  int i = blockIdx.x * 256 + threadIdx.x;
  if (i < Nn) {
    int blk = i >> 10;
    int basev = blk ? bsum[blk - 1] : 0;
    int o = loc[i] + basev;
    off[i] = o;
    cursor[i] = o;
  }
  if (i == 0) off[Nn] = ET;
}

__global__ __launch_bounds__(256) void fill_k(const int* __restrict__ ei, int E, int Nn,
                                              int* __restrict__ cursor, int* __restrict__ srcs) {
  int e = blockIdx.x * blockDim.x + threadIdx.x;
  int ET = E + Nn;
  if (e >= ET) return;
  int src, dst;
  if (e < E) { src = ei[e]; dst = ei[E + e]; }
  else { src = e - E; dst = e - E; }
  int pos = atomicAdd(&cursor[dst], 1);
  srcs[pos] = src;
}

// ---------------------------------------------------------------------------
// Layer-1 aggregation: wave per dst node, 3 heads x 64 ch, bf16 gathers,
// 2-way edge unroll. Softmax without max-subtraction; bias + ELU fused.
// ---------------------------------------------------------------------------
__global__ __launch_bounds__(256) void agg1_k(const unsigned short* __restrict__ Hb,
                                              const float* __restrict__ a_s,
                                              const float* __restrict__ a_d,
                                              const int* __restrict__ off,
                                              const int* __restrict__ srcs,
                                              const float* __restrict__ bias,
                                              float* __restrict__ out, int Nn) {
  int wave = threadIdx.x >> 6, lane = threadIdx.x & 63;
  int node = blockIdx.x * 4 + wave;
  if (node >= Nn) return;
  float ad0 = a_d[(size_t)node * 3 + 0];
  float ad1 = a_d[(size_t)node * 3 + 1];
  float ad2 = a_d[(size_t)node * 3 + 2];
  int b = off[node], e = off[node + 1];
  float acc0 = 0.f, acc1 = 0.f, acc2 = 0.f, ts0 = 0.f, ts1 = 0.f, ts2 = 0.f;
  int p = b;
  for (; p + 2 <= e; p += 2) {
    int s0 = srcs[p], s1 = srcs[p + 1];
    const float* as0 = a_s + (size_t)s0 * 3;
    const float* as1 = a_s + (size_t)s1 * 3;
    const unsigned short* h0 = Hb + (size_t)s0 * 192;
    const unsigned short* h1 = Hb + (size_t)s1 * 192;
    float u00 = bf2f(h0[lane]), u01 = bf2f(h0[64 + lane]), u02 = bf2f(h0[128 + lane]);
    float u10 = bf2f(h1[lane]), u11 = bf2f(h1[64 + lane]), u12 = bf2f(h1[128 + lane]);
    float t00 = __expf(lrelu(as0[0] + ad0));
    float t01 = __expf(lrelu(as0[1] + ad1));
    float t02 = __expf(lrelu(as0[2] + ad2));
    float t10 = __expf(lrelu(as1[0] + ad0));
    float t11 = __expf(lrelu(as1[1] + ad1));
    float t12 = __expf(lrelu(as1[2] + ad2));
    acc0 = fmaf(t00, u00, acc0); acc0 = fmaf(t10, u10, acc0);
    acc1 = fmaf(t01, u01, acc1); acc1 = fmaf(t11, u11, acc1);
    acc2 = fmaf(t02, u02, acc2); acc2 = fmaf(t12, u12, acc2);
    ts0 += t00 + t10; ts1 += t01 + t11; ts2 += t02 + t12;
  }
  if (p < e) {
    int s = srcs[p];
    const float* asp = a_s + (size_t)s * 3;
    const unsigned short* hp = Hb + (size_t)s * 192;
    float t0 = __expf(lrelu(asp[0] + ad0));
    float t1 = __expf(lrelu(asp[1] + ad1));
    float t2 = __expf(lrelu(asp[2] + ad2));
    acc0 = fmaf(t0, bf2f(hp[lane]), acc0);
    acc1 = fmaf(t1, bf2f(hp[64 + lane]), acc1);
    acc2 = fmaf(t2, bf2f(hp[128 + lane]), acc2);
    ts0 += t0; ts1 += t1; ts2 += t2;
  }
  float o0 = acc0 / (ts0 + EPS_DEN) + bias[lane];
  float o1 = acc1 / (ts1 + EPS_DEN) + bias[64 + lane];
  float o2 = acc2 / (ts2 + EPS_DEN) + bias[128 + lane];
  o0 = o0 > 0.f ? o0 : expm1f(o0);
  o1 = o1 > 0.f ? o1 : expm1f(o1);
  o2 = o2 > 0.f ? o2 : expm1f(o2);
  out[(size_t)node * 192 + lane] = o0;
  out[(size_t)node * 192 + 64 + lane] = o1;
  out[(size_t)node * 192 + 128 + lane] = o2;
}

// ---------------------------------------------------------------------------
// Layer-2 aggregation: wave per dst node, single head x 64 ch, bf16 gathers,
// 2-way unroll. Writes f32 d_out.
// ---------------------------------------------------------------------------
__global__ __launch_bounds__(256) void agg2_k(const unsigned short* __restrict__ Hb,
                                              const float* __restrict__ a_s,
                                              const float* __restrict__ a_d,
                                              const int* __restrict__ off,
                                              const int* __restrict__ srcs,
                                              const float* __restrict__ bias,
                                              float* __restrict__ out, int Nn) {
  int wave = threadIdx.x >> 6, lane = threadIdx.x & 63;
  int node = blockIdx.x * 4 + wave;
  if (node >= Nn) return;
  float ad = a_d[node];
  int b = off[node], e = off[node + 1];
  float acc = 0.f, ts = 0.f;
  int p = b;
  for (; p + 2 <= e; p += 2) {
    int s0 = srcs[p], s1 = srcs[p + 1];
    float u0 = bf2f(Hb[(size_t)s0 * 64 + lane]);
    float u1 = bf2f(Hb[(size_t)s1 * 64 + lane]);
    float t0 = __expf(lrelu(a_s[s0] + ad));
    float t1 = __expf(lrelu(a_s[s1] + ad));
    acc = fmaf(t0, u0, acc);
    acc = fmaf(t1, u1, acc);
    ts += t0 + t1;
  }
  if (p < e) {
    int s = srcs[p];
    float t = __expf(lrelu(a_s[s] + ad));
    acc = fmaf(t, bf2f(Hb[(size_t)s * 64 + lane]), acc);
    ts += t;
  }
  out[(size_t)node * 64 + lane] = acc / (ts + EPS_DEN) + bias[lane];
}

// ---------------------------------------------------------------------------
extern "C" void kernel_launch(void* const* d_in, const int* in_sizes, int n_in,
                              void* d_out, int out_size, void* d_ws, size_t ws_size,
                              hipStream_t stream) {
  const float* x = (const float*)d_in[0];
  const int* ei = (const int*)d_in[1];
  const float* W1 = (const float*)d_in[2];
  const float* att_src1 = (const float*)d_in[3];
  const float* att_dst1 = (const float*)d_in[4];
  const float* b1 = (const float*)d_in[5];
  const float* W2 = (const float*)d_in[6];
  const float* att_src2 = (const float*)d_in[7];
  const float* att_dst2 = (const float*)d_in[8];
  const float* b2 = (const float*)d_in[9];

  const int IN = 128, HEADS = 3, HID = 64, OUT = 64;
  const int HC1 = HEADS * HID;  // 192
  const int N = in_sizes[0] / IN;
  const int E = in_sizes[1] / 2;
  const int ET = E + N;

  // workspace layout
  float* ws = (float*)d_ws;
  float* h1_post = ws;                          // N*192 f32
  float* a_s1 = h1_post + (size_t)N * HC1;      // N*3
  float* a_d1 = a_s1 + (size_t)N * HEADS;       // N*3
  float* a_s2 = a_d1 + (size_t)N * HEADS;       // N
  float* a_d2 = a_s2 + N;                       // N
  int* deg = (int*)(a_d2 + N);                  // N
  int* off = deg + N;                           // N+1
  int* cursor = off + (N + 1);                  // N
  int* bsum = cursor + N;                       // 64
  int* srcs = bsum + 64;                        // ET
  unsigned short* h1b = (unsigned short*)(srcs + ET);        // N*192 bf16
  unsigned short* h2b = h1b + (size_t)N * HC1;               // N*64 bf16

  float* outp = (float*)d_out;

  int gemm_blocks = (N + 63) / 64;
  int row_blocks = (N + 3) / 4;
  int edge_blocks = (ET + 255) / 256;
  int nblk = (N + 1023) / 1024;

  // CSR build (graph identical for both layers)
  hipMemsetAsync(deg, 0, (size_t)N * sizeof(int), stream);
  deg_count_k<<<edge_blocks, 256, 0, stream>>>(ei, E, N, deg);
  scan1_k<<<nblk, 256, 0, stream>>>(deg, cursor, bsum, N);
  scan2_k<<<1, 64, 0, stream>>>(bsum, nblk);
  scan3_k<<<(N + 255) / 256, 256, 0, stream>>>(cursor, bsum, off, cursor, N, ET);
  fill_k<<<edge_blocks, 256, 0, stream>>>(ei, E, N, cursor, srcs);

  // Layer 1
  gemm_k<128, 192><<<gemm_blocks, 256, 0, stream>>>(x, W1, h1b, att_src1, att_dst1,
                                                    a_s1, a_d1, N);
  agg1_k<<<row_blocks, 256, 0, stream>>>(h1b, a_s1, a_d1, off, srcs, b1, h1_post, N);

  // Layer 2
  gemm_k<192, 64><<<gemm_blocks, 256, 0, stream>>>(h1_post, W2, h2b, att_src2, att_dst2,
                                                   a_s2, a_d2, N);
  agg2_k<<<row_blocks, 256, 0, stream>>>(h2b, a_s2, a_d2, off, srcs, b2, outp, N);

  (void)n_in; (void)out_size; (void)ws_size;
}